// Round 1
// baseline (639.285 us; speedup 1.0000x reference)
//
#include <hip/hip_runtime.h>
#include <math.h>

#define BATCH 64
#define IC 2048
// J = M = N = 16
#define NW  16              // waves per block (1024 threads), one i per wave
#define NIB NW              // 16 i's per block
#define NGB (IC / NIB)      // 128 i-groups
#define BSPL 2              // b-split: each block does 32 b's
#define NBB (BATCH / BSPL)  // 32
// grid = NGB * BSPL = 256 blocks = 1/CU, 16 waves = 4/SIMD

// Lane map: j = lane&15 (softmax dim), mg = lane>>4 (m = 4mg..4mg+3 as float4).
// m-reduce = shfl_xor 16,32 ; softmax-over-j = shfl_xor 1,2,4,8.
// ONE i per wave -> W fragment is 16 float4 = 64 VGPRs, guaranteed resident
// under the 128-VGPR cap a 1024-thread block implies (4 waves/SIMD).
template <bool FIRST>
__global__ __launch_bounds__(1024, 4) void pass_kernel(
    const float* __restrict__ Wt,      // [IC, 16, 16, 16]  (i, j, n, m)
    const float* __restrict__ inp,     // [BATCH, IC, 16]
    const float* __restrict__ vcum,    // [BATCH, 16, 16]   (b, j, m)
    float* __restrict__ partial)       // [NGB, BATCH, 256]
{
    const int tid  = threadIdx.x;
    const int wave = tid >> 6;
    const int lane = tid & 63;
    const int j    = lane & 15;
    const int mg   = lane >> 4;
    const int bi   = blockIdx.x;
    const int g    = (bi & 7) | ((bi >> 4) << 3);   // twins bi, bi+8 -> same XCD
    const int half = (bi >> 3) & 1;
    const int b0   = half * NBB;
    const int i    = g * NIB + wave;

    // block-shared accumulator, lane-contiguous layout: [bloc][lane + 64*c]
    __shared__ float lacc[NBB * 256];   // 32 KB
    for (int t = tid; t < NBB * 64; t += NW * 64)
        *(float4*)&lacc[t * 4] = make_float4(0.f, 0.f, 0.f, 0.f);

    // resident W fragment: w[n] = W[i, j, n, 4mg..4mg+3]
    const float4* wp = (const float4*)Wt + ((size_t)i * 1024 + j * 64 + mg);
    float4 w[16];
#pragma unroll
    for (int n = 0; n < 16; ++n) w[n] = wp[n * 4];

    __syncthreads();   // lacc zeros visible

    const int bst = (wave * 2) & (NBB - 1);   // stagger waves across b
    int bloc = bst;
    // prefetch b-iteration 0: u = inputs[b, i, 0..15] (64 B, wave-uniform addr)
    const float4* up = (const float4*)(inp + ((size_t)(b0 + bloc) * IC + i) * 16);
    float4 u[4];
#pragma unroll
    for (int q = 0; q < 4; ++q) u[q] = up[q];
    float4 vcn;
    if (!FIRST)
        vcn = *(const float4*)(vcum + (b0 + bloc) * 256 + j * 16 + mg * 4);

    for (int bb = 0; bb < NBB; ++bb) {
        const int cb = bloc;
        float4 uc[4];
#pragma unroll
        for (int q = 0; q < 4; ++q) uc[q] = u[q];
        const float4 vcc = vcn;
        // issue next-b loads before compute (SW pipeline)
        bloc = (bst + bb + 1) & (NBB - 1);
        if (bb + 1 < NBB) {
            const float4* upn = (const float4*)(inp + ((size_t)(b0 + bloc) * IC + i) * 16);
#pragma unroll
            for (int q = 0; q < 4; ++q) u[q] = upn[q];
            if (!FIRST)
                vcn = *(const float4*)(vcum + (b0 + bloc) * 256 + j * 16 + mg * 4);
        }

        float4 h = make_float4(0.f, 0.f, 0.f, 0.f);
#define ACC4(H, W, S)                                                   \
        (H).x = fmaf((W).x, (S), (H).x); (H).y = fmaf((W).y, (S), (H).y); \
        (H).z = fmaf((W).z, (S), (H).z); (H).w = fmaf((W).w, (S), (H).w);
        ACC4(h, w[0],  uc[0].x) ACC4(h, w[1],  uc[0].y)
        ACC4(h, w[2],  uc[0].z) ACC4(h, w[3],  uc[0].w)
        ACC4(h, w[4],  uc[1].x) ACC4(h, w[5],  uc[1].y)
        ACC4(h, w[6],  uc[1].z) ACC4(h, w[7],  uc[1].w)
        ACC4(h, w[8],  uc[2].x) ACC4(h, w[9],  uc[2].y)
        ACC4(h, w[10], uc[2].z) ACC4(h, w[11], uc[2].w)
        ACC4(h, w[12], uc[3].x) ACC4(h, w[13], uc[3].y)
        ACC4(h, w[14], uc[3].z) ACC4(h, w[15], uc[3].w)
#undef ACC4

        float4 a;
        if (FIRST) {
            a = h;
        } else {
            // logit for this i's routing chain
            float t = h.x * vcc.x + h.y * vcc.y + h.z * vcc.z + h.w * vcc.w;
            t += __shfl_xor(t, 16);
            t += __shfl_xor(t, 32);
            const float e = __expf(t);
            float s = e;
            s += __shfl_xor(s, 1);
            s += __shfl_xor(s, 2);
            s += __shfl_xor(s, 4);
            s += __shfl_xor(s, 8);
            const float c = e * __builtin_amdgcn_rcpf(s);
            a.x = c * h.x; a.y = c * h.y; a.z = c * h.z; a.w = c * h.w;
        }
        // conflict-free (2-way) LDS atomic accumulate: addr = lane + 64*c
        float* lp = &lacc[cb * 256 + lane];
        atomicAdd(lp,       a.x);
        atomicAdd(lp + 64,  a.y);
        atomicAdd(lp + 128, a.z);
        atomicAdd(lp + 192, a.w);
    }
    __syncthreads();

    // write partial in standard [b][j*16+m] layout, coalesced float4 stores.
    // stored el(e): e=4q+c -> lds addr = ob*256 + (q&3)*16 + (q>>2) + 64*c
#pragma unroll
    for (int r = 0; r < (NBB * 64) / (NW * 64); ++r) {   // 2 iters
        const int idx = r * (NW * 64) + tid;
        const int ob  = idx >> 6;
        const int q   = idx & 63;
        const int base = ob * 256 + ((q & 3) << 4) + (q >> 2);
        float4 v;
        v.x = lacc[base];
        v.y = lacc[base + 64];
        v.z = lacc[base + 128];
        v.w = lacc[base + 192];
        *(float4*)(partial + ((size_t)g * BATCH + b0 + ob) * 256 + q * 4) = v;
    }
}

// Grid = BATCH*4 blocks of 64 threads. Reduce over NGB groups, squash
// (m-sum intra-wave: e = j*16+m, shfl 1,2,4,8), update vcum / write out.
__global__ __launch_bounds__(64) void reduce_squash(
    const float* __restrict__ partial, float* __restrict__ vcum,
    float* __restrict__ out, int stage)
{
    const int b = blockIdx.x >> 2;
    const int q = blockIdx.x & 3;
    const int e = q * 64 + threadIdx.x;
    const float* p = partial + (size_t)b * 256 + e;
    float s = 0.0f;
#pragma unroll 8
    for (int gi = 0; gi < NGB; ++gi)
        s += p[(size_t)gi * BATCH * 256];
    if (stage == 0) s *= (1.0f / 16.0f);   // uniform c = 1/16 on iteration 0

    float n2 = s * s;
    n2 += __shfl_xor(n2, 1);
    n2 += __shfl_xor(n2, 2);
    n2 += __shfl_xor(n2, 4);
    n2 += __shfl_xor(n2, 8);
    const float scale = n2 / ((1.0f + n2) * sqrtf(n2 + 1e-8f));
    const float v = scale * s;

    const int o = b * 256 + e;
    if (stage == 0)      vcum[o] = v;
    else if (stage == 1) vcum[o] += v;
    else                 out[o] = v;
}

extern "C" void kernel_launch(void* const* d_in, const int* in_sizes, int n_in,
                              void* d_out, int out_size, void* d_ws, size_t ws_size,
                              hipStream_t stream) {
    const float* inp = (const float*)d_in[0];   // [64, 2048, 16]
    const float* Wt  = (const float*)d_in[1];   // [2048, 16, 16, 16]
    float* out = (float*)d_out;                 // [64, 16, 16]
    float* partial = (float*)d_ws;              // NGB*BATCH*256 floats = 8.4 MB
    float* vcum = partial + (size_t)NGB * BATCH * 256;  // 64 KB

    const dim3 gp(NGB * BSPL), bp(NW * 64);
    const dim3 gr(BATCH * 4), br(64);

    // iter 0: c uniform -> s0 ; v0 = squash(s0/16); vcum = v0
    pass_kernel<true><<<gp, bp, 0, stream>>>(Wt, inp, nullptr, partial);
    reduce_squash<<<gr, br, 0, stream>>>(partial, vcum, out, 0);
    // iter 1: logits from vcum=v0 -> s1 ; vcum += v1
    pass_kernel<false><<<gp, bp, 0, stream>>>(Wt, inp, vcum, partial);
    reduce_squash<<<gr, br, 0, stream>>>(partial, vcum, out, 1);
    // iter 2: logits from vcum=v0+v1 -> s2 ; out = squash(s2)
    pass_kernel<false><<<gp, bp, 0, stream>>>(Wt, inp, vcum, partial);
    reduce_squash<<<gr, br, 0, stream>>>(partial, vcum, out, 2);
}

// Round 2
// 395.044 us; speedup vs baseline: 1.6183x; 1.6183x over previous
//
#include <hip/hip_runtime.h>
#include <math.h>

#define BATCH 64
#define IC 2048
// J = M = N = 16
#define NIW 2               // i's per wave, W resident in VGPRs (128 regs)
#define NW  8               // waves per block (512 threads)
#define NIB (NIW * NW)      // 16 i's per block
#define NGB (IC / NIB)      // 128 i-groups
#define BSPL 2              // b-split: each block does 32 b's
#define NBB (BATCH / BSPL)  // 32
// grid = NGB * BSPL = 256 blocks = 1/CU, 8 waves = 2/SIMD

// Lane map: j = lane&15 (softmax dim), mg = lane>>4 (m = 4mg..4mg+3 as float4).
// m-reduce = shfl_xor 16,32 ; softmax-over-j = shfl_xor 1,2,4,8.
// W residency is FORCED via an empty-asm register pin at the top of the
// b-loop: creates a loop-carried dep on every w component so the compiler
// cannot sink/rematerialize the loads into the loop (rounds 0-1 showed it
// does exactly that: VGPR_Count 116/64 < the W array size).
template <bool FIRST>
__global__ __launch_bounds__(512, 2) void pass_kernel(
    const float* __restrict__ Wt,      // [IC, 16, 16, 16]  (i, j, n, m)
    const float* __restrict__ inp,     // [BATCH, IC, 16]
    const float* __restrict__ vcum,    // [BATCH, 16, 16]   (b, j, m)
    float* __restrict__ partial)       // [NGB, BATCH, 256]
{
    const int tid  = threadIdx.x;
    const int wave = tid >> 6;
    const int lane = tid & 63;
    const int j    = lane & 15;
    const int mg   = lane >> 4;
    const int bi   = blockIdx.x;
    const int g    = (bi & 7) | ((bi >> 4) << 3);   // twins bi, bi+8 -> same XCD
    const int half = (bi >> 3) & 1;
    const int b0   = half * NBB;
    const int ibase = g * NIB + wave * NIW;

    // block-shared accumulator, lane-contiguous layout: [bloc][lane + 64*c]
    __shared__ float lacc[NBB * 256];   // 32 KB
    for (int t = tid; t < NBB * 64; t += 512)
        *(float4*)&lacc[t * 4] = make_float4(0.f, 0.f, 0.f, 0.f);

    // resident W fragments: w[n] = W[i, j, n, 4mg..4mg+3]
    const float4* wp = (const float4*)Wt + ((size_t)ibase * 1024 + j * 64 + mg);
    float4 w0[16], w1[16];
#pragma unroll
    for (int n = 0; n < 16; ++n) { w0[n] = wp[n * 4]; w1[n] = wp[1024 + n * 4]; }

    __syncthreads();   // lacc zeros visible

    const int bst = (wave * 4) & (NBB - 1);   // stagger waves across b
    int bloc = bst;
    // prefetch b-iteration 0: u covers both i's (128 B contiguous)
    const float4* up = (const float4*)(inp + ((size_t)(b0 + bloc) * IC + ibase) * 16);
    float4 u[8];
#pragma unroll
    for (int q = 0; q < 8; ++q) u[q] = up[q];
    float4 vcn;
    if (!FIRST)
        vcn = *(const float4*)(vcum + (b0 + bloc) * 256 + j * 16 + mg * 4);

    for (int bb = 0; bb < NBB; ++bb) {
        // ---- register pin: forces w0/w1 to stay resident across the loop ----
#pragma unroll
        for (int n = 0; n < 16; ++n) {
            asm volatile("" : "+v"(w0[n].x), "+v"(w0[n].y),
                              "+v"(w0[n].z), "+v"(w0[n].w),
                              "+v"(w1[n].x), "+v"(w1[n].y),
                              "+v"(w1[n].z), "+v"(w1[n].w));
        }
        const int cb = bloc;
        float4 uc[8];
#pragma unroll
        for (int q = 0; q < 8; ++q) uc[q] = u[q];
        const float4 vcc = vcn;
        // issue next-b loads before compute (SW pipeline)
        bloc = (bst + bb + 1) & (NBB - 1);
        if (bb + 1 < NBB) {
            const float4* upn = (const float4*)(inp + ((size_t)(b0 + bloc) * IC + ibase) * 16);
#pragma unroll
            for (int q = 0; q < 8; ++q) u[q] = upn[q];
            if (!FIRST)
                vcn = *(const float4*)(vcum + (b0 + bloc) * 256 + j * 16 + mg * 4);
        }

        float4 h0 = make_float4(0.f, 0.f, 0.f, 0.f);
        float4 h1 = make_float4(0.f, 0.f, 0.f, 0.f);
#define ACC4(H, W, S)                                                   \
        (H).x = fmaf((W).x, (S), (H).x); (H).y = fmaf((W).y, (S), (H).y); \
        (H).z = fmaf((W).z, (S), (H).z); (H).w = fmaf((W).w, (S), (H).w);
        ACC4(h0, w0[0],  uc[0].x) ACC4(h0, w0[1],  uc[0].y)
        ACC4(h0, w0[2],  uc[0].z) ACC4(h0, w0[3],  uc[0].w)
        ACC4(h0, w0[4],  uc[1].x) ACC4(h0, w0[5],  uc[1].y)
        ACC4(h0, w0[6],  uc[1].z) ACC4(h0, w0[7],  uc[1].w)
        ACC4(h0, w0[8],  uc[2].x) ACC4(h0, w0[9],  uc[2].y)
        ACC4(h0, w0[10], uc[2].z) ACC4(h0, w0[11], uc[2].w)
        ACC4(h0, w0[12], uc[3].x) ACC4(h0, w0[13], uc[3].y)
        ACC4(h0, w0[14], uc[3].z) ACC4(h0, w0[15], uc[3].w)
        ACC4(h1, w1[0],  uc[4].x) ACC4(h1, w1[1],  uc[4].y)
        ACC4(h1, w1[2],  uc[4].z) ACC4(h1, w1[3],  uc[4].w)
        ACC4(h1, w1[4],  uc[5].x) ACC4(h1, w1[5],  uc[5].y)
        ACC4(h1, w1[6],  uc[5].z) ACC4(h1, w1[7],  uc[5].w)
        ACC4(h1, w1[8],  uc[6].x) ACC4(h1, w1[9],  uc[6].y)
        ACC4(h1, w1[10], uc[6].z) ACC4(h1, w1[11], uc[6].w)
        ACC4(h1, w1[12], uc[7].x) ACC4(h1, w1[13], uc[7].y)
        ACC4(h1, w1[14], uc[7].z) ACC4(h1, w1[15], uc[7].w)
#undef ACC4

        float4 a;
        if (FIRST) {
            a.x = h0.x + h1.x; a.y = h0.y + h1.y;
            a.z = h0.z + h1.z; a.w = h0.w + h1.w;
        } else {
            // logits for both i's (independent routing chains, ILP-friendly)
            float t0 = h0.x * vcc.x + h0.y * vcc.y + h0.z * vcc.z + h0.w * vcc.w;
            float t1 = h1.x * vcc.x + h1.y * vcc.y + h1.z * vcc.z + h1.w * vcc.w;
            t0 += __shfl_xor(t0, 16); t1 += __shfl_xor(t1, 16);
            t0 += __shfl_xor(t0, 32); t1 += __shfl_xor(t1, 32);
            const float e0 = __expf(t0), e1 = __expf(t1);
            float s0 = e0, s1 = e1;
            s0 += __shfl_xor(s0, 1); s1 += __shfl_xor(s1, 1);
            s0 += __shfl_xor(s0, 2); s1 += __shfl_xor(s1, 2);
            s0 += __shfl_xor(s0, 4); s1 += __shfl_xor(s1, 4);
            s0 += __shfl_xor(s0, 8); s1 += __shfl_xor(s1, 8);
            const float c0 = e0 * __builtin_amdgcn_rcpf(s0);
            const float c1 = e1 * __builtin_amdgcn_rcpf(s1);
            a.x = fmaf(c0, h0.x, c1 * h1.x);
            a.y = fmaf(c0, h0.y, c1 * h1.y);
            a.z = fmaf(c0, h0.z, c1 * h1.z);
            a.w = fmaf(c0, h0.w, c1 * h1.w);
        }
        // conflict-free (2-way) LDS atomic accumulate: addr = lane + 64*c
        float* lp = &lacc[cb * 256 + lane];
        atomicAdd(lp,       a.x);
        atomicAdd(lp + 64,  a.y);
        atomicAdd(lp + 128, a.z);
        atomicAdd(lp + 192, a.w);
    }
    __syncthreads();

    // write partial in standard [b][j*16+m] layout, coalesced float4 stores.
    // stored el(e): e=4q+c -> lds addr = ob*256 + (q&3)*16 + (q>>2) + 64*c
#pragma unroll
    for (int r = 0; r < (NBB * 64) / 512; ++r) {   // 4 iters
        const int idx = r * 512 + tid;
        const int ob  = idx >> 6;
        const int q   = idx & 63;
        const int base = ob * 256 + ((q & 3) << 4) + (q >> 2);
        float4 v;
        v.x = lacc[base];
        v.y = lacc[base + 64];
        v.z = lacc[base + 128];
        v.w = lacc[base + 192];
        *(float4*)(partial + ((size_t)g * BATCH + b0 + ob) * 256 + q * 4) = v;
    }
}

// Grid = BATCH*4 blocks of 64 threads. Reduce over NGB groups, squash
// (m-sum intra-wave: e = j*16+m, shfl 1,2,4,8), update vcum / write out.
__global__ __launch_bounds__(64) void reduce_squash(
    const float* __restrict__ partial, float* __restrict__ vcum,
    float* __restrict__ out, int stage)
{
    const int b = blockIdx.x >> 2;
    const int q = blockIdx.x & 3;
    const int e = q * 64 + threadIdx.x;
    const float* p = partial + (size_t)b * 256 + e;
    float s = 0.0f;
#pragma unroll 8
    for (int gi = 0; gi < NGB; ++gi)
        s += p[(size_t)gi * BATCH * 256];
    if (stage == 0) s *= (1.0f / 16.0f);   // uniform c = 1/16 on iteration 0

    float n2 = s * s;
    n2 += __shfl_xor(n2, 1);
    n2 += __shfl_xor(n2, 2);
    n2 += __shfl_xor(n2, 4);
    n2 += __shfl_xor(n2, 8);
    const float scale = n2 / ((1.0f + n2) * sqrtf(n2 + 1e-8f));
    const float v = scale * s;

    const int o = b * 256 + e;
    if (stage == 0)      vcum[o] = v;
    else if (stage == 1) vcum[o] += v;
    else                 out[o] = v;
}

extern "C" void kernel_launch(void* const* d_in, const int* in_sizes, int n_in,
                              void* d_out, int out_size, void* d_ws, size_t ws_size,
                              hipStream_t stream) {
    const float* inp = (const float*)d_in[0];   // [64, 2048, 16]
    const float* Wt  = (const float*)d_in[1];   // [2048, 16, 16, 16]
    float* out = (float*)d_out;                 // [64, 16, 16]
    float* partial = (float*)d_ws;              // NGB*BATCH*256 floats = 8.4 MB
    float* vcum = partial + (size_t)NGB * BATCH * 256;  // 64 KB

    const dim3 gp(NGB * BSPL), bp(512);
    const dim3 gr(BATCH * 4), br(64);

    // iter 0: c uniform -> s0 ; v0 = squash(s0/16); vcum = v0
    pass_kernel<true><<<gp, bp, 0, stream>>>(Wt, inp, nullptr, partial);
    reduce_squash<<<gr, br, 0, stream>>>(partial, vcum, out, 0);
    // iter 1: logits from vcum=v0 -> s1 ; vcum += v1
    pass_kernel<false><<<gp, bp, 0, stream>>>(Wt, inp, vcum, partial);
    reduce_squash<<<gr, br, 0, stream>>>(partial, vcum, out, 1);
    // iter 2: logits from vcum=v0+v1 -> s2 ; out = squash(s2)
    pass_kernel<false><<<gp, bp, 0, stream>>>(Wt, inp, vcum, partial);
    reduce_squash<<<gr, br, 0, stream>>>(partial, vcum, out, 2);
}